// Round 5
// baseline (122.828 us; speedup 1.0000x reference)
//
#include <hip/hip_runtime.h>
#include <math.h>

#define Bdim 8
#define Cdim 64
#define Ndim 4096
#define NT   (Ndim / 64)
#define HT   (NT / 2)          // tiles per key-group

typedef __bf16 bf16x8 __attribute__((ext_vector_type(8)));
typedef __bf16 bf16x4 __attribute__((ext_vector_type(4)));
typedef float  f32x4  __attribute__((ext_vector_type(4)));

__device__ __forceinline__ float fexp2(float x) {
#if __has_builtin(__builtin_amdgcn_exp2f)
    return __builtin_amdgcn_exp2f(x);
#else
    return exp2f(x);
#endif
}

// ---------------------------------------------------------------------------
// Kernel 0: convert w_qkv to bf16 hi/lo (12288 elems).
// ---------------------------------------------------------------------------
__global__ __launch_bounds__(256) void wconv_kernel(
    const float* __restrict__ w, __bf16* __restrict__ whi, __bf16* __restrict__ wlo)
{
    const int i = blockIdx.x * 256 + threadIdx.x;
    const float v = w[i];
    const __bf16 h = (__bf16)v;
    whi[i] = h;
    wlo[i] = (__bf16)(v - (float)h);
}

// ---------------------------------------------------------------------------
// Kernel 1: QKV projection via MFMA, hi/lo split (~fp32 precision).
// D[j][n] = sum_c W[j][c] X[c][n];  A = W (row li), B = X (col li).
// Grid 512 (b, 64-n tile) x 256 thr; wave wv owns n-subtile wv*16, 12 j-tiles.
//   Qb [B][N][C], Kb [B][N][C], Vb [B][C][N]   (bf16)
// ---------------------------------------------------------------------------
__global__ __launch_bounds__(256) void qkv_mfma_kernel(
    const float* __restrict__ x,
    const __bf16* __restrict__ whi, const __bf16* __restrict__ wlo,
    __bf16* __restrict__ Qb, __bf16* __restrict__ Kb, __bf16* __restrict__ Vb)
{
    const int bx   = blockIdx.x;
    const int b    = bx >> 6;
    const int nblk = bx & 63;
    const int tid  = threadIdx.x;
    const int wv   = tid >> 6;
    const int l    = tid & 63;
    const int g    = l >> 4;
    const int li   = l & 15;
    const int nbase = nblk * 64 + wv * 16;

    // X B-frags: B[k=kc*32+8g+jj][col=li], hi/lo split
    bf16x8 xhi[2], xlo[2];
#pragma unroll
    for (int kc = 0; kc < 2; ++kc)
#pragma unroll
        for (int jj = 0; jj < 8; ++jj) {
            const int c = kc * 32 + 8 * g + jj;
            const float v = x[((size_t)(b * 64 + c)) * Ndim + nbase + li];
            const __bf16 h = (__bf16)v;
            xhi[kc][jj] = h;
            xlo[kc][jj] = (__bf16)(v - (float)h);
        }

#pragma unroll
    for (int jt = 0; jt < 12; ++jt) {
        const int j = 16 * jt + li;
        const __bf16* wh = whi + j * 64;
        const __bf16* wl = wlo + j * 64;
        const bf16x8 ah0 = *(const bf16x8*)(wh + 8 * g);
        const bf16x8 ah1 = *(const bf16x8*)(wh + 32 + 8 * g);
        const bf16x8 al0 = *(const bf16x8*)(wl + 8 * g);
        const bf16x8 al1 = *(const bf16x8*)(wl + 32 + 8 * g);
        f32x4 d = (f32x4){0.f, 0.f, 0.f, 0.f};
        d = __builtin_amdgcn_mfma_f32_16x16x32_bf16(ah0, xhi[0], d, 0, 0, 0);
        d = __builtin_amdgcn_mfma_f32_16x16x32_bf16(ah1, xhi[1], d, 0, 0, 0);
        d = __builtin_amdgcn_mfma_f32_16x16x32_bf16(ah0, xlo[0], d, 0, 0, 0);
        d = __builtin_amdgcn_mfma_f32_16x16x32_bf16(ah1, xlo[1], d, 0, 0, 0);
        d = __builtin_amdgcn_mfma_f32_16x16x32_bf16(al0, xhi[0], d, 0, 0, 0);
        d = __builtin_amdgcn_mfma_f32_16x16x32_bf16(al1, xhi[1], d, 0, 0, 0);

        // lane holds D[j = 16jt+4g+r][n = nbase+li], r=0..3
        if (jt < 8) {
            bf16x4 pk;
#pragma unroll
            for (int r = 0; r < 4; ++r) pk[r] = (__bf16)d[r];
            __bf16* dst = ((jt < 4) ? Qb : Kb)
                          + ((size_t)b * Ndim + nbase + li) * 64 + ((jt & 3) * 16 + 4 * g);
            *(bf16x4*)dst = pk;   // 8B aligned (col % 4 == 0)
        } else {
#pragma unroll
            for (int r = 0; r < 4; ++r) {
                const int cv = (jt - 8) * 16 + 4 * g + r;
                Vb[((size_t)(b * 64 + cv)) * Ndim + nbase + li] = (__bf16)d[r];
            }
        }
    }
}

// ---------------------------------------------------------------------------
// Kernel 2: MFMA flash attention, split-key 8-wave blocks, pi-permuted K.
// Single-buffered LDS (33 KB) + T14 async staging (global->reg early,
// ds_write after barrier, depth-2 pipeline). T13 defer-max (THR=8, log2).
// LDS layout byte-identical to round 4 (validated): write-side XOR swizzle
// granule^(row&7), read paths unchanged.
// ---------------------------------------------------------------------------
__global__ __launch_bounds__(512, 6) void attn_kernel(
    const __bf16* __restrict__ Qb, const __bf16* __restrict__ Kb,
    const __bf16* __restrict__ Vb, const int* __restrict__ fg,
    const float* __restrict__ w_proj, const float* __restrict__ b_proj,
    float* __restrict__ out)
{
    __shared__ __align__(16) unsigned char smem[2 * 8192 + 2 * 8192 + 2 * 64 * 4];
    __bf16* kt  = (__bf16*)smem;              // [grp][64][64]
    __bf16* vt  = (__bf16*)(smem + 16384);    // [grp][64][64]
    float*  mtf = (float*)(smem + 32768);     // [grp][64]
    float*  mrg = (float*)smem;               // epilogue overlay (18 KB)

    const int bx   = blockIdx.x;
    const int b    = bx >> 6;
    const int qblk = bx & 63;
    const int tid  = threadIdx.x;
    const int wv   = tid >> 6;
    const int grp  = wv >> 2;
    const int wsub = wv & 3;
    const int l    = tid & 63;
    const int g    = l >> 4;
    const int li   = l & 15;

    // Q B-frags: B[k=c][col=qrow]; lane reads Q[qrow][8g..] contiguous.
    const int qrow = qblk * 64 + wsub * 16 + li;
    const __bf16* qbase = Qb + (((size_t)b * Ndim + qrow) * 64);
    const bf16x8 qa0 = *(const bf16x8*)(qbase + 8 * g);
    const bf16x8 qa1 = *(const bf16x8*)(qbase + 32 + 8 * g);

    // Staging geometry: wave stages LDS rows srow..srow+15.
    const int srow = wsub * 16;
    const int lrow = l >> 3;                  // 0..7
    const int gr   = l & 7;                   // 16B granule (linear on source)
    // pi for K rows: R = 16*wsub + lrow  ->  pi(R)
    const int pi0 = 8 * (lrow >> 2) + 32 * (wsub >> 1) + 4 * (wsub & 1) + (lrow & 3);
    const __bf16* ksrcL = Kb + (((size_t)b * Ndim + pi0) * 64) + 8 * gr;
    const __bf16* vsrcL = Vb + (((size_t)(b * 64) + srow + lrow) * Ndim) + 8 * gr;
    // LDS write offsets (write-side swizzle: granule ^ (row&7))
    const int wOff = (srow + lrow) * 64 + 8 * (gr ^ lrow);
    __bf16* ktw = kt + grp * 4096;
    __bf16* vtw = vt + grp * 4096;

    const int t0 = grp * HT;

    uint4 kr0, kr1, vr0, vr1;
    int fgv = 0;
    auto stage_load = [&](int t) {
        const __bf16* kp = ksrcL + (size_t)t * 4096;
        kr0 = *(const uint4*)kp;
        kr1 = *(const uint4*)(kp + 16 * 64);
        const __bf16* vp = vsrcL + t * 64;
        vr0 = *(const uint4*)vp;
        vr1 = *(const uint4*)(vp + 8 * Ndim);
        if (wsub == 0) fgv = fg[b * Ndim + t * 64 + l];
    };
    auto stage_write = [&]() {
        *(uint4*)(ktw + wOff)       = kr0;
        *(uint4*)(ktw + wOff + 512) = kr1;
        *(uint4*)(vtw + wOff)       = vr0;
        *(uint4*)(vtw + wOff + 512) = vr1;
        if (wsub == 0) mtf[grp * 64 + l] = fgv ? 0.f : -1e30f;
    };

    f32x4 accv[4];
#pragma unroll
    for (int ct = 0; ct < 4; ++ct) accv[ct] = (f32x4){0.f, 0.f, 0.f, 0.f};
    float mrun = -1e30f, lrun = 0.f;

    stage_load(t0);
    stage_write();
    if (HT > 1) stage_load(t0 + 1);
    __syncthreads();

    const float KS = 0.125f * 1.44269504089f;   // (1/sqrt(C)) * log2(e)

    for (int it = 0; it < HT; ++it) {
        // mask bias: key(st,r) = 8g + 32*(st>>1) + 4*(st&1) + r
        f32x4 mb[4];
        mb[0] = *(const f32x4*)(&mtf[grp * 64 + 8 * g]);
        mb[1] = *(const f32x4*)(&mtf[grp * 64 + 8 * g + 4]);
        mb[2] = *(const f32x4*)(&mtf[grp * 64 + 8 * g + 32]);
        mb[3] = *(const f32x4*)(&mtf[grp * 64 + 8 * g + 36]);

        // ---- S^T = K Q^T (rows are pi-permuted keys) ----
        f32x4 s2[4];
        __builtin_amdgcn_s_setprio(1);
#pragma unroll
        for (int st = 0; st < 4; ++st) {
            const int R  = 16 * st + li;
            const int sw = (li & 7) * 8;
            const bf16x8 kb0 = *(const bf16x8*)(&ktw[R * 64 + ((8 * g) ^ sw)]);
            const bf16x8 kb1 = *(const bf16x8*)(&ktw[R * 64 + ((32 + 8 * g) ^ sw)]);
            f32x4 z = (f32x4){0.f, 0.f, 0.f, 0.f};
            z = __builtin_amdgcn_mfma_f32_16x16x32_bf16(kb0, qa0, z, 0, 0, 0);
            z = __builtin_amdgcn_mfma_f32_16x16x32_bf16(kb1, qa1, z, 0, 0, 0);
#pragma unroll
            for (int r = 0; r < 4; ++r) s2[st][r] = z[r] * KS + mb[st][r];
        }
        __builtin_amdgcn_s_setprio(0);

        // ---- online softmax with T13 defer-max (log2 domain, THR=8) ----
        float tm = -1e30f;
#pragma unroll
        for (int st = 0; st < 4; ++st) {
            const float a = fmaxf(fmaxf(s2[st][0], s2[st][1]),
                                  fmaxf(s2[st][2], s2[st][3]));
            tm = fmaxf(tm, a);
        }
        tm = fmaxf(tm, __shfl_xor(tm, 16));
        tm = fmaxf(tm, __shfl_xor(tm, 32));

        if (!__all(tm - mrun <= 8.f)) {
            const float mnew = fmaxf(mrun, tm);
            const float sc   = fexp2(mrun - mnew);
            mrun = mnew;
            lrun *= sc;
#pragma unroll
            for (int ct = 0; ct < 4; ++ct)
#pragma unroll
                for (int r = 0; r < 4; ++r) accv[ct][r] *= sc;
        }

        f32x4 p[4];
        float ps = 0.f;
#pragma unroll
        for (int st = 0; st < 4; ++st)
#pragma unroll
            for (int r = 0; r < 4; ++r) {
                const float e = fexp2(s2[st][r] - mrun);
                p[st][r] = e;
                ps += e;
            }
        ps += __shfl_xor(ps, 16);
        ps += __shfl_xor(ps, 32);
        lrun += ps;

        // ---- P B-frags = the lane's own registers ----
        bf16x8 pb01, pb23;
#pragma unroll
        for (int r = 0; r < 4; ++r) {
            pb01[r]     = (__bf16)p[0][r];
            pb01[4 + r] = (__bf16)p[1][r];
            pb23[r]     = (__bf16)p[2][r];
            pb23[4 + r] = (__bf16)p[3][r];
        }

        // ---- O^T += V^T P^T : V A-frags contiguous b128 ----
        __builtin_amdgcn_s_setprio(1);
#pragma unroll
        for (int ct = 0; ct < 4; ++ct) {
            const int c = 16 * ct + li;
            const bf16x8 vf0 = *(const bf16x8*)(&vtw[c * 64 + 8 * (g ^ (c & 7))]);
            const bf16x8 vf1 = *(const bf16x8*)(&vtw[c * 64 + 8 * ((4 + g) ^ (c & 7))]);
            accv[ct] = __builtin_amdgcn_mfma_f32_16x16x32_bf16(vf0, pb01, accv[ct], 0, 0, 0);
            accv[ct] = __builtin_amdgcn_mfma_f32_16x16x32_bf16(vf1, pb23, accv[ct], 0, 0, 0);
        }
        __builtin_amdgcn_s_setprio(0);

        // ---- staged write of next tile + issue loads for tile after ----
        if (it + 1 < HT) {
            __syncthreads();              // all reads of current tile done
            stage_write();                // regs(t0+it+1) -> LDS
            if (it + 2 < HT) stage_load(t0 + it + 2);
            __syncthreads();              // writes visible
        }
    }

    // ---- merge group 1 into group 0 via LDS overlay ----
    __syncthreads();                     // all tile reads done
    if (grp == 1) {
        if (g == 0) {
            mrg[wsub * 128 + li * 2 + 0] = mrun;
            mrg[wsub * 128 + li * 2 + 1] = lrun;
        }
        float* o1 = mrg + 512 + ((size_t)(wsub * 64 + l)) * 16;
#pragma unroll
        for (int ct = 0; ct < 4; ++ct)
            *(f32x4*)(o1 + 4 * ct) = accv[ct];
    }
    __syncthreads();
    if (grp == 1) return;

    const float m1 = mrg[wsub * 128 + li * 2 + 0];
    const float l1 = mrg[wsub * 128 + li * 2 + 1];
    const float m  = fmaxf(mrun, m1);
    const float a0 = fexp2(mrun - m);
    const float a1 = fexp2(m1 - m);
    const float inv = 1.f / (lrun * a0 + l1 * a1);
    const float* o1 = mrg + 512 + ((size_t)(wsub * 64 + l)) * 16;

    bf16x8 ob01, ob23;
#pragma unroll
    for (int r = 0; r < 4; ++r) {
        ob01[r]     = (__bf16)((accv[0][r] * a0 + o1[0 + r]  * a1) * inv);
        ob01[4 + r] = (__bf16)((accv[1][r] * a0 + o1[4 + r]  * a1) * inv);
        ob23[r]     = (__bf16)((accv[2][r] * a0 + o1[8 + r]  * a1) * inv);
        ob23[4 + r] = (__bf16)((accv[3][r] * a0 + o1[12 + r] * a1) * inv);
    }

    // ---- fused out-projection ----
    const int nbase = qblk * 64 + wsub * 16;
#pragma unroll
    for (int cot = 0; cot < 4; ++cot) {
        const int co = 16 * cot + li;
        const float* wr = w_proj + co * 64;
        const float4 f0 = *(const float4*)(wr + 4 * g);
        const float4 f1 = *(const float4*)(wr + 16 + 4 * g);
        const float4 f2 = *(const float4*)(wr + 32 + 4 * g);
        const float4 f3 = *(const float4*)(wr + 48 + 4 * g);
        bf16x8 wf0, wf1;
        wf0[0] = (__bf16)f0.x; wf0[1] = (__bf16)f0.y; wf0[2] = (__bf16)f0.z; wf0[3] = (__bf16)f0.w;
        wf0[4] = (__bf16)f1.x; wf0[5] = (__bf16)f1.y; wf0[6] = (__bf16)f1.z; wf0[7] = (__bf16)f1.w;
        wf1[0] = (__bf16)f2.x; wf1[1] = (__bf16)f2.y; wf1[2] = (__bf16)f2.z; wf1[3] = (__bf16)f2.w;
        wf1[4] = (__bf16)f3.x; wf1[5] = (__bf16)f3.y; wf1[6] = (__bf16)f3.z; wf1[7] = (__bf16)f3.w;

        f32x4 y = (f32x4){0.f, 0.f, 0.f, 0.f};
        y = __builtin_amdgcn_mfma_f32_16x16x32_bf16(wf0, ob01, y, 0, 0, 0);
        y = __builtin_amdgcn_mfma_f32_16x16x32_bf16(wf1, ob23, y, 0, 0, 0);

        const f32x4 bp = *(const f32x4*)(b_proj + 16 * cot + 4 * g);
#pragma unroll
        for (int r = 0; r < 4; ++r) {
            const int co_s = 16 * cot + 4 * g + r;
            out[((size_t)(b * 64 + co_s)) * Ndim + nbase + li] = y[r] + bp[r];
        }
    }
}

extern "C" void kernel_launch(void* const* d_in, const int* in_sizes, int n_in,
                              void* d_out, int out_size, void* d_ws, size_t ws_size,
                              hipStream_t stream) {
    const float* x      = (const float*)d_in[0];
    const int*   fg     = (const int*)d_in[1];
    const float* w_qkv  = (const float*)d_in[2];
    const float* w_proj = (const float*)d_in[3];
    const float* b_proj = (const float*)d_in[4];
    float* out = (float*)d_out;

    const size_t per = (size_t)Bdim * Cdim * Ndim;   // 2,097,152 elems
    __bf16* Qb  = (__bf16*)d_ws;
    __bf16* Kb  = Qb + per;
    __bf16* Vb  = Kb + per;
    __bf16* Whi = Vb + per;
    __bf16* Wlo = Whi + 3 * Cdim * Cdim;

    wconv_kernel<<<dim3(3 * Cdim * Cdim / 256), dim3(256), 0, stream>>>(
        w_qkv, Whi, Wlo);
    qkv_mfma_kernel<<<dim3(Bdim * (Ndim / 64)), dim3(256), 0, stream>>>(
        x, Whi, Wlo, Qb, Kb, Vb);
    attn_kernel<<<dim3(Bdim * (Ndim / 64)), dim3(512), 0, stream>>>(
        Qb, Kb, Vb, fg, w_proj, b_proj, out);
}

// Round 6
// 87.414 us; speedup vs baseline: 1.4051x; 1.4051x over previous
//
#include <hip/hip_runtime.h>
#include <math.h>

#define Bdim 8
#define Cdim 64
#define Ndim 4096
#define NT   (Ndim / 64)
#define HT   (NT / 2)          // tiles per key-group

typedef __bf16 bf16x8 __attribute__((ext_vector_type(8)));
typedef __bf16 bf16x4 __attribute__((ext_vector_type(4)));
typedef float  f32x4  __attribute__((ext_vector_type(4)));

__device__ __forceinline__ void gload_lds16(const void* g, void* l) {
    __builtin_amdgcn_global_load_lds(
        (const __attribute__((address_space(1))) void*)g,
        (__attribute__((address_space(3))) void*)l, 16, 0, 0);
}

__device__ __forceinline__ float fexp2(float x) {
#if __has_builtin(__builtin_amdgcn_exp2f)
    return __builtin_amdgcn_exp2f(x);
#else
    return exp2f(x);
#endif
}

// ---------------------------------------------------------------------------
// Kernel 0: convert w_qkv to bf16 hi/lo (12288 elems).
// ---------------------------------------------------------------------------
__global__ __launch_bounds__(256) void wconv_kernel(
    const float* __restrict__ w, __bf16* __restrict__ whi, __bf16* __restrict__ wlo)
{
    const int i = blockIdx.x * 256 + threadIdx.x;
    const float v = w[i];
    const __bf16 h = (__bf16)v;
    whi[i] = h;
    wlo[i] = (__bf16)(v - (float)h);
}

// ---------------------------------------------------------------------------
// Kernel 1: QKV projection via MFMA, hi/lo split (~fp32 precision).
// D[j][n] = sum_c W[j][c] X[c][n];  A = W (row li), B = X (col li).
// Q is pre-scaled by (1/sqrt(C))*log2(e) so attention's QK^T lands directly
// in the log2-softmax domain.
//   Qb [B][N][C], Kb [B][N][C], Vb [B][C][N]   (bf16)
// ---------------------------------------------------------------------------
__global__ __launch_bounds__(256) void qkv_mfma_kernel(
    const float* __restrict__ x,
    const __bf16* __restrict__ whi, const __bf16* __restrict__ wlo,
    __bf16* __restrict__ Qb, __bf16* __restrict__ Kb, __bf16* __restrict__ Vb)
{
    const int bx   = blockIdx.x;
    const int b    = bx >> 6;
    const int nblk = bx & 63;
    const int tid  = threadIdx.x;
    const int wv   = tid >> 6;
    const int l    = tid & 63;
    const int g    = l >> 4;
    const int li   = l & 15;
    const int nbase = nblk * 64 + wv * 16;

    const float KS = 0.125f * 1.44269504089f;

    // X B-frags: B[k=kc*32+8g+jj][col=li], hi/lo split
    bf16x8 xhi[2], xlo[2];
#pragma unroll
    for (int kc = 0; kc < 2; ++kc)
#pragma unroll
        for (int jj = 0; jj < 8; ++jj) {
            const int c = kc * 32 + 8 * g + jj;
            const float v = x[((size_t)(b * 64 + c)) * Ndim + nbase + li];
            const __bf16 h = (__bf16)v;
            xhi[kc][jj] = h;
            xlo[kc][jj] = (__bf16)(v - (float)h);
        }

#pragma unroll
    for (int jt = 0; jt < 12; ++jt) {
        const int j = 16 * jt + li;
        const __bf16* wh = whi + j * 64;
        const __bf16* wl = wlo + j * 64;
        const bf16x8 ah0 = *(const bf16x8*)(wh + 8 * g);
        const bf16x8 ah1 = *(const bf16x8*)(wh + 32 + 8 * g);
        const bf16x8 al0 = *(const bf16x8*)(wl + 8 * g);
        const bf16x8 al1 = *(const bf16x8*)(wl + 32 + 8 * g);
        f32x4 d = (f32x4){0.f, 0.f, 0.f, 0.f};
        d = __builtin_amdgcn_mfma_f32_16x16x32_bf16(ah0, xhi[0], d, 0, 0, 0);
        d = __builtin_amdgcn_mfma_f32_16x16x32_bf16(ah1, xhi[1], d, 0, 0, 0);
        d = __builtin_amdgcn_mfma_f32_16x16x32_bf16(ah0, xlo[0], d, 0, 0, 0);
        d = __builtin_amdgcn_mfma_f32_16x16x32_bf16(ah1, xlo[1], d, 0, 0, 0);
        d = __builtin_amdgcn_mfma_f32_16x16x32_bf16(al0, xhi[0], d, 0, 0, 0);
        d = __builtin_amdgcn_mfma_f32_16x16x32_bf16(al1, xhi[1], d, 0, 0, 0);

        // lane holds D[j = 16jt+4g+r][n = nbase+li], r=0..3
        if (jt < 8) {
            const float qs = (jt < 4) ? KS : 1.f;   // pre-scale Q only
            bf16x4 pk;
#pragma unroll
            for (int r = 0; r < 4; ++r) pk[r] = (__bf16)(d[r] * qs);
            __bf16* dst = ((jt < 4) ? Qb : Kb)
                          + ((size_t)b * Ndim + nbase + li) * 64 + ((jt & 3) * 16 + 4 * g);
            *(bf16x4*)dst = pk;   // 8B aligned (col % 4 == 0)
        } else {
#pragma unroll
            for (int r = 0; r < 4; ++r) {
                const int cv = (jt - 8) * 16 + 4 * g + r;
                Vb[((size_t)(b * 64 + cv)) * Ndim + nbase + li] = (__bf16)d[r];
            }
        }
    }
}

// ---------------------------------------------------------------------------
// Kernel 2: MFMA flash attention, split-key 8-wave blocks, pi-permuted K.
// Round-4 structure (double-buffered gload_lds, 1 barrier/tile) + deltas:
// mask bias as MFMA accumulator init, T13 defer-max, T5 setprio.
// ---------------------------------------------------------------------------
__global__ __launch_bounds__(512, 4) void attn_kernel(
    const __bf16* __restrict__ Qb, const __bf16* __restrict__ Kb,
    const __bf16* __restrict__ Vb, const int* __restrict__ fg,
    const float* __restrict__ w_proj, const float* __restrict__ b_proj,
    float* __restrict__ out)
{
    __shared__ __align__(16) __bf16 kt[2][2][64 * 64];  // [grp][buf][R][c]
    __shared__ __align__(16) __bf16 vt[2][2][64 * 64];  // [grp][buf][c][key]
    __shared__ float mtf[2][2][64];                     // mask bias by key

    const int bx   = blockIdx.x;
    const int b    = bx >> 6;
    const int qblk = bx & 63;
    const int tid  = threadIdx.x;
    const int wv   = tid >> 6;
    const int grp  = wv >> 2;
    const int wsub = wv & 3;
    const int l    = tid & 63;
    const int g    = l >> 4;
    const int li   = l & 15;

    // Q B-frags: B[k=c][col=qrow]; lane reads Q[qrow][8g..] contiguous.
    const int qrow = qblk * 64 + wsub * 16 + li;
    const __bf16* qbase = Qb + (((size_t)b * Ndim + qrow) * 64);
    const bf16x8 qa0 = *(const bf16x8*)(qbase + 8 * g);
    const bf16x8 qa1 = *(const bf16x8*)(qbase + 32 + 8 * g);

    // Staging: wave stages LDS rows srow..srow+15 (2 gload calls of 8 rows).
    const int srow = wsub * 16;
    const int lrow = l >> 3;
    const int lgr  = 8 * ((l & 7) ^ lrow);   // 16B-granule XOR swizzle (src side)
    const int pi0 = 8 * (lrow >> 2) + 32 * (wsub >> 1) + 4 * (wsub & 1) + (lrow & 3);
    const __bf16* ksrc0 = Kb + (((size_t)b * Ndim + pi0) * 64) + lgr;       // pi1 = pi0+16
    const __bf16* vsrc0 = Vb + (((size_t)(b * 64) + srow + lrow) * Ndim) + lgr;

    const int t0 = grp * HT;

    auto stage = [&](int t, int buf) {
        const size_t ko = (size_t)t * 4096;
        gload_lds16(ksrc0 + ko,             &kt[grp][buf][srow * 64]);
        gload_lds16(ksrc0 + ko + 16 * 64,   &kt[grp][buf][(srow + 8) * 64]);
        gload_lds16(vsrc0 + t * 64,             &vt[grp][buf][srow * 64]);
        gload_lds16(vsrc0 + t * 64 + 8 * Ndim,  &vt[grp][buf][(srow + 8) * 64]);
        if (wsub == 0)
            mtf[grp][buf][l] = fg[b * Ndim + t * 64 + l] ? 0.f : -1e30f;
    };

    f32x4 accv[4];
#pragma unroll
    for (int ct = 0; ct < 4; ++ct) accv[ct] = (f32x4){0.f, 0.f, 0.f, 0.f};
    float mrun = -1e30f, lrun = 0.f;

    stage(t0, 0);

    for (int it = 0; it < HT; ++it) {
        const int buf = it & 1;
        __syncthreads();                  // tile t0+it resident
        if (it + 1 < HT) stage(t0 + it + 1, buf ^ 1);

        // mask bias: key(st,r) = 8g + 32*(st>>1) + 4*(st&1) + r
        f32x4 mb[4];
        mb[0] = *(const f32x4*)(&mtf[grp][buf][8 * g]);
        mb[1] = *(const f32x4*)(&mtf[grp][buf][8 * g + 4]);
        mb[2] = *(const f32x4*)(&mtf[grp][buf][8 * g + 32]);
        mb[3] = *(const f32x4*)(&mtf[grp][buf][8 * g + 36]);

        // ---- S^T = K Q^T + mask (acc-init), Q pre-scaled to log2 domain ----
        f32x4 s2[4];
        __builtin_amdgcn_s_setprio(1);
#pragma unroll
        for (int st = 0; st < 4; ++st) {
            const int R  = 16 * st + li;
            const int sw = (li & 7) * 8;
            const bf16x8 kb0 = *(const bf16x8*)(&kt[grp][buf][R * 64 + ((8 * g) ^ sw)]);
            const bf16x8 kb1 = *(const bf16x8*)(&kt[grp][buf][R * 64 + ((32 + 8 * g) ^ sw)]);
            f32x4 z = mb[st];
            z = __builtin_amdgcn_mfma_f32_16x16x32_bf16(kb0, qa0, z, 0, 0, 0);
            z = __builtin_amdgcn_mfma_f32_16x16x32_bf16(kb1, qa1, z, 0, 0, 0);
            s2[st] = z;
        }
        __builtin_amdgcn_s_setprio(0);

        // ---- online softmax with T13 defer-max (log2 domain, THR=8) ----
        float tm = -1e30f;
#pragma unroll
        for (int st = 0; st < 4; ++st) {
            const float a = fmaxf(fmaxf(s2[st][0], s2[st][1]),
                                  fmaxf(s2[st][2], s2[st][3]));
            tm = fmaxf(tm, a);
        }
        tm = fmaxf(tm, __shfl_xor(tm, 16));
        tm = fmaxf(tm, __shfl_xor(tm, 32));

        if (!__all(tm - mrun <= 8.f)) {
            const float mnew = fmaxf(mrun, tm);
            const float sc   = fexp2(mrun - mnew);
            mrun = mnew;
            lrun *= sc;
#pragma unroll
            for (int ct = 0; ct < 4; ++ct)
#pragma unroll
                for (int r = 0; r < 4; ++r) accv[ct][r] *= sc;
        }

        f32x4 p[4];
        float ps = 0.f;
#pragma unroll
        for (int st = 0; st < 4; ++st)
#pragma unroll
            for (int r = 0; r < 4; ++r) {
                const float e = fexp2(s2[st][r] - mrun);
                p[st][r] = e;
                ps += e;
            }
        ps += __shfl_xor(ps, 16);
        ps += __shfl_xor(ps, 32);
        lrun += ps;

        // ---- P B-frags = the lane's own registers ----
        bf16x8 pb01, pb23;
#pragma unroll
        for (int r = 0; r < 4; ++r) {
            pb01[r]     = (__bf16)p[0][r];
            pb01[4 + r] = (__bf16)p[1][r];
            pb23[r]     = (__bf16)p[2][r];
            pb23[4 + r] = (__bf16)p[3][r];
        }

        // ---- O^T += V^T P^T : V A-frags are contiguous b128 reads ----
        __builtin_amdgcn_s_setprio(1);
#pragma unroll
        for (int ct = 0; ct < 4; ++ct) {
            const int c = 16 * ct + li;
            const bf16x8 vf0 = *(const bf16x8*)(&vt[grp][buf][c * 64 + 8 * (g ^ (c & 7))]);
            const bf16x8 vf1 = *(const bf16x8*)(&vt[grp][buf][c * 64 + 8 * ((4 + g) ^ (c & 7))]);
            accv[ct] = __builtin_amdgcn_mfma_f32_16x16x32_bf16(vf0, pb01, accv[ct], 0, 0, 0);
            accv[ct] = __builtin_amdgcn_mfma_f32_16x16x32_bf16(vf1, pb23, accv[ct], 0, 0, 0);
        }
        __builtin_amdgcn_s_setprio(0);
    }

    // ---- merge group 1 into group 0 via LDS overlay on kt ----
    float* mrg = (float*)&kt[0][0][0];
    __syncthreads();                     // all tile reads done
    if (grp == 1) {
        if (g == 0) {
            mrg[wsub * 128 + li * 2 + 0] = mrun;
            mrg[wsub * 128 + li * 2 + 1] = lrun;
        }
        float* o1 = mrg + 512 + ((size_t)(wsub * 64 + l)) * 16;
#pragma unroll
        for (int ct = 0; ct < 4; ++ct)
            *(f32x4*)(o1 + 4 * ct) = accv[ct];
    }
    __syncthreads();
    if (grp == 1) return;

    const float m1 = mrg[wsub * 128 + li * 2 + 0];
    const float l1 = mrg[wsub * 128 + li * 2 + 1];
    const float m  = fmaxf(mrun, m1);
    const float a0 = fexp2(mrun - m);
    const float a1 = fexp2(m1 - m);
    const float inv = 1.f / (lrun * a0 + l1 * a1);
    const float* o1 = mrg + 512 + ((size_t)(wsub * 64 + l)) * 16;

    bf16x8 ob01, ob23;
#pragma unroll
    for (int r = 0; r < 4; ++r) {
        ob01[r]     = (__bf16)((accv[0][r] * a0 + o1[0 + r]  * a1) * inv);
        ob01[4 + r] = (__bf16)((accv[1][r] * a0 + o1[4 + r]  * a1) * inv);
        ob23[r]     = (__bf16)((accv[2][r] * a0 + o1[8 + r]  * a1) * inv);
        ob23[4 + r] = (__bf16)((accv[3][r] * a0 + o1[12 + r] * a1) * inv);
    }

    // ---- fused out-projection ----
    const int nbase = qblk * 64 + wsub * 16;
#pragma unroll
    for (int cot = 0; cot < 4; ++cot) {
        const int co = 16 * cot + li;
        const float* wr = w_proj + co * 64;
        const float4 f0 = *(const float4*)(wr + 4 * g);
        const float4 f1 = *(const float4*)(wr + 16 + 4 * g);
        const float4 f2 = *(const float4*)(wr + 32 + 4 * g);
        const float4 f3 = *(const float4*)(wr + 48 + 4 * g);
        bf16x8 wf0, wf1;
        wf0[0] = (__bf16)f0.x; wf0[1] = (__bf16)f0.y; wf0[2] = (__bf16)f0.z; wf0[3] = (__bf16)f0.w;
        wf0[4] = (__bf16)f1.x; wf0[5] = (__bf16)f1.y; wf0[6] = (__bf16)f1.z; wf0[7] = (__bf16)f1.w;
        wf1[0] = (__bf16)f2.x; wf1[1] = (__bf16)f2.y; wf1[2] = (__bf16)f2.z; wf1[3] = (__bf16)f2.w;
        wf1[4] = (__bf16)f3.x; wf1[5] = (__bf16)f3.y; wf1[6] = (__bf16)f3.z; wf1[7] = (__bf16)f3.w;

        f32x4 y = (f32x4){0.f, 0.f, 0.f, 0.f};
        y = __builtin_amdgcn_mfma_f32_16x16x32_bf16(wf0, ob01, y, 0, 0, 0);
        y = __builtin_amdgcn_mfma_f32_16x16x32_bf16(wf1, ob23, y, 0, 0, 0);

        const f32x4 bp = *(const f32x4*)(b_proj + 16 * cot + 4 * g);
#pragma unroll
        for (int r = 0; r < 4; ++r) {
            const int co_s = 16 * cot + 4 * g + r;
            out[((size_t)(b * 64 + co_s)) * Ndim + nbase + li] = y[r] + bp[r];
        }
    }
}

extern "C" void kernel_launch(void* const* d_in, const int* in_sizes, int n_in,
                              void* d_out, int out_size, void* d_ws, size_t ws_size,
                              hipStream_t stream) {
    const float* x      = (const float*)d_in[0];
    const int*   fg     = (const int*)d_in[1];
    const float* w_qkv  = (const float*)d_in[2];
    const float* w_proj = (const float*)d_in[3];
    const float* b_proj = (const float*)d_in[4];
    float* out = (float*)d_out;

    const size_t per = (size_t)Bdim * Cdim * Ndim;   // 2,097,152 elems
    __bf16* Qb  = (__bf16*)d_ws;
    __bf16* Kb  = Qb + per;
    __bf16* Vb  = Kb + per;
    __bf16* Whi = Vb + per;
    __bf16* Wlo = Whi + 3 * Cdim * Cdim;

    wconv_kernel<<<dim3(3 * Cdim * Cdim / 256), dim3(256), 0, stream>>>(
        w_qkv, Whi, Wlo);
    qkv_mfma_kernel<<<dim3(Bdim * (Ndim / 64)), dim3(256), 0, stream>>>(
        x, Whi, Wlo, Qb, Kb, Vb);
    attn_kernel<<<dim3(Bdim * (Ndim / 64)), dim3(512), 0, stream>>>(
        Qb, Kb, Vb, fg, w_proj, b_proj, out);
}